// Round 7
// baseline (133.739 us; speedup 1.0000x reference)
//
#include <hip/hip_runtime.h>

// Problem constants (match reference)
constexpr int B = 16;
constexpr int N = 100000;
constexpr int E = 10;

typedef float        f32x4 __attribute__((ext_vector_type(4)));
typedef unsigned int u32x2 __attribute__((ext_vector_type(2)));
typedef unsigned int u32x4 __attribute__((ext_vector_type(4)));

__device__ __forceinline__ unsigned int bf16_rne(float f) {
    unsigned int u = __float_as_uint(f);
    u += 0x7fffu + ((u >> 16) & 1u);   // round-to-nearest-even
    return u >> 16;
}
__device__ __forceinline__ float bf16_lo(unsigned int w) { return __uint_as_float(w << 16); }
__device__ __forceinline__ float bf16_hi(unsigned int w) { return __uint_as_float(w & 0xffff0000u); }

// ---------------------------------------------------------------------------
// diff kernel: diff = coord2 - coord1 packed as bf16 {x,y,z,pad} 8B/node.
// Also zeroes the output accumulator (replaces the memset dispatch).
// ---------------------------------------------------------------------------
__global__ __launch_bounds__(256) void diff_bf16_kernel(const float* __restrict__ c1,
                                                        const float* __restrict__ c2,
                                                        unsigned int* __restrict__ outp,
                                                        float* __restrict__ out,
                                                        int nquad) {  // B*N/4
    if (blockIdx.x == 0 && threadIdx.x == 0) *out = 0.0f;
    int per = gridDim.x >> 3;
    int w = (blockIdx.x & 7) * per + (blockIdx.x >> 3);
    int i = w * blockDim.x + threadIdx.x;
    if (i >= nquad) return;
    const f32x4* a4 = reinterpret_cast<const f32x4*>(c1) + (size_t)i * 3;
    const f32x4* b4 = reinterpret_cast<const f32x4*>(c2) + (size_t)i * 3;
    f32x4 a0 = __builtin_nontemporal_load(a4 + 0);
    f32x4 a1 = __builtin_nontemporal_load(a4 + 1);
    f32x4 a2 = __builtin_nontemporal_load(a4 + 2);
    f32x4 b0 = __builtin_nontemporal_load(b4 + 0);
    f32x4 b1 = __builtin_nontemporal_load(b4 + 1);
    f32x4 b2 = __builtin_nontemporal_load(b4 + 2);
    float d[12];
    d[0] = b0.x - a0.x; d[1] = b0.y - a0.y; d[2]  = b0.z - a0.z; d[3]  = b0.w - a0.w;
    d[4] = b1.x - a1.x; d[5] = b1.y - a1.y; d[6]  = b1.z - a1.z; d[7]  = b1.w - a1.w;
    d[8] = b2.x - a2.x; d[9] = b2.y - a2.y; d[10] = b2.z - a2.z; d[11] = b2.w - a2.w;

    u32x4 o0, o1;
    o0.x = bf16_rne(d[0]) | (bf16_rne(d[1]) << 16);
    o0.y = bf16_rne(d[2]);
    o0.z = bf16_rne(d[3]) | (bf16_rne(d[4]) << 16);
    o0.w = bf16_rne(d[5]);
    o1.x = bf16_rne(d[6]) | (bf16_rne(d[7]) << 16);
    o1.y = bf16_rne(d[8]);
    o1.z = bf16_rne(d[9]) | (bf16_rne(d[10]) << 16);
    o1.w = bf16_rne(d[11]);

    u32x4* o = reinterpret_cast<u32x4*>(outp) + (size_t)i * 2;
    o[0] = o0;
    o[1] = o1;
}

// ---------------------------------------------------------------------------
// LDS-tiled loss kernel.
// 512 blocks x 1024 threads. Block g: batch b=(g&7)+8*((g>>3)&1) (XCD-affine),
// node range [slot*3125, slot*3125+3125) with slot=g>>4. Each thread owns 4
// node-slots; its 40 neighbor indices live in registers for all 13 passes.
// The batch diff slab streams through a 64KB LDS tile (8192 nodes/pass) with
// register-staged double buffering; gathers are exec-masked ds_read_b64.
// ---------------------------------------------------------------------------
constexpr int TPB   = 1024;
constexpr int SLOTS = 32;            // blocks per batch
constexpr int NPB   = N / SLOTS;     // 3125 nodes per block (exact)
constexpr int NPT   = 4;             // ceil(3125/1024) node-slots per thread
constexpr int TILE  = 8192;          // nodes per LDS tile = 64KB
constexpr int NPASS = (N + TILE - 1) / TILE;  // 13
constexpr int SPT   = TILE / TPB;    // 8 staged entries per thread
constexpr int LOSS_BLOCKS = B * SLOTS;        // 512

__global__ __launch_bounds__(TPB, 4) void loss_tiled(const unsigned int* __restrict__ diff,
                                                     const int* __restrict__ A,
                                                     float* __restrict__ out) {
    __shared__ u32x2 tile[TILE];     // 64 KB

    const int g = blockIdx.x;
    const int b = (g & 7) + 8 * ((g >> 3) & 1);   // batch, XCD-affine
    const int base = (g >> 4) * NPB;              // node range start
    const int t = threadIdx.x;
    const u32x2 zv = {0u, 0u};

    const u32x2* db = reinterpret_cast<const u32x2*>(diff) + (size_t)b * N;

    // ---- load A rows; indices held in registers for the whole kernel ----
    int idx[NPT][E];
    float cnt[NPT];
    float sx[NPT], sy[NPT], sz[NPT];
    #pragma unroll
    for (int s = 0; s < NPT; ++s) {
        sx[s] = sy[s] = sz[s] = 0.f;
        int l = s * TPB + t;                 // 0..4095 (3125.. inactive)
        bool a = (l < NPB);
        int node = b * N + base + (a ? l : 0);
        const long long* ap = reinterpret_cast<const long long*>(A + (size_t)node * E);
        long long q0 = __builtin_nontemporal_load(ap + 0);
        long long q1 = __builtin_nontemporal_load(ap + 1);
        long long q2 = __builtin_nontemporal_load(ap + 2);
        long long q3 = __builtin_nontemporal_load(ap + 3);
        long long q4 = __builtin_nontemporal_load(ap + 4);
        idx[s][0] = a ? (int)q0 : -1;  idx[s][1] = a ? (int)(q0 >> 32) : -1;
        idx[s][2] = a ? (int)q1 : -1;  idx[s][3] = a ? (int)(q1 >> 32) : -1;
        idx[s][4] = a ? (int)q2 : -1;  idx[s][5] = a ? (int)(q2 >> 32) : -1;
        idx[s][6] = a ? (int)q3 : -1;  idx[s][7] = a ? (int)(q3 >> 32) : -1;
        idx[s][8] = a ? (int)q4 : -1;  idx[s][9] = a ? (int)(q4 >> 32) : -1;
        float c = 0.f;
        #pragma unroll
        for (int e = 0; e < E; ++e) c += (idx[s][e] >= 0) ? 1.f : 0.f;
        cnt[s] = a ? c : 1.f;                // avoid 1/0 for inactive slots
    }

    // ---- prologue: stage + write tile for pass 0 ----
    u32x2 stg[SPT];
    #pragma unroll
    for (int k = 0; k < SPT; ++k) {
        int j = k * TPB + t;
        stg[k] = (j < N) ? db[j] : zv;
    }
    #pragma unroll
    for (int k = 0; k < SPT; ++k) tile[k * TPB + t] = stg[k];

    // ---- pass loop ----
    #pragma unroll 1
    for (int p = 0; p < NPASS; ++p) {
        __syncthreads();                     // tile p fully written
        const int lo = p * TILE;
        if (p + 1 < NPASS) {                 // issue next tile's global loads
            const int lo2 = lo + TILE;
            #pragma unroll
            for (int k = 0; k < SPT; ++k) {
                int j = lo2 + k * TPB + t;
                stg[k] = (j < N) ? db[j] : zv;
            }
        }
        // gather from LDS: only indices inside [lo, lo+TILE)
        #pragma unroll
        for (int s = 0; s < NPT; ++s) {
            #pragma unroll
            for (int e = 0; e < E; ++e) {
                unsigned r = (unsigned)(idx[s][e] - lo);
                if (r < (unsigned)TILE) {
                    u32x2 v = tile[r];
                    sx[s] += bf16_lo(v.x);
                    sy[s] += bf16_hi(v.x);
                    sz[s] += bf16_lo(v.y);
                }
            }
        }
        __syncthreads();                     // everyone done reading tile p
        if (p + 1 < NPASS) {
            #pragma unroll
            for (int k = 0; k < SPT; ++k) tile[k * TPB + t] = stg[k];
        }
    }

    // ---- epilogue: lap = own - centroid; square; reduce ----
    float acc = 0.f;
    #pragma unroll
    for (int s = 0; s < NPT; ++s) {
        int l = s * TPB + t;
        bool a = (l < NPB);
        u32x2 ov = db[base + (a ? l : 0)];   // coalesced own read
        float inv = 1.0f / cnt[s];
        float lx = bf16_lo(ov.x) - sx[s] * inv;
        float ly = bf16_hi(ov.x) - sy[s] * inv;
        float lz = bf16_lo(ov.y) - sz[s] * inv;
        float sq = lx * lx + ly * ly + lz * lz;
        acc += a ? sq : 0.f;
    }

    #pragma unroll
    for (int off = 32; off > 0; off >>= 1)
        acc += __shfl_down(acc, off, 64);

    __syncthreads();                         // tile no longer needed: reuse as scratch
    float* red = reinterpret_cast<float*>(tile);
    if ((t & 63) == 0) red[t >> 6] = acc;
    __syncthreads();
    if (t == 0) {
        float tot = 0.f;
        #pragma unroll
        for (int i = 0; i < TPB / 64; ++i) tot += red[i];
        // loss = sum/(B*N*D) * N = sum/(B*D) = sum/48
        atomicAdd(out, tot * (1.0f / 48.0f));
    }
}

extern "C" void kernel_launch(void* const* d_in, const int* in_sizes, int n_in,
                              void* d_out, int out_size, void* d_ws, size_t ws_size,
                              hipStream_t stream) {
    const float* coord1 = (const float*)d_in[0];
    const float* coord2 = (const float*)d_in[1];
    const int* A_list = (const int*)d_in[2];
    float* out = (float*)d_out;
    unsigned int* diff = (unsigned int*)d_ws;   // B*N*8 bytes = 12.8 MB

    int nodes = B * N;       // 1.6M
    int nquad = nodes / 4;   // 400000
    int dblk = (nquad + 255) / 256;  // 1563
    dblk = (dblk + 7) & ~7;          // 1568, multiple of 8 for swizzle
    diff_bf16_kernel<<<dblk, 256, 0, stream>>>(coord1, coord2, diff, out, nquad);

    loss_tiled<<<LOSS_BLOCKS, TPB, 0, stream>>>(diff, A_list, out);
}

// Round 8
// 107.617 us; speedup vs baseline: 1.2427x; 1.2427x over previous
//
#include <hip/hip_runtime.h>

// Problem constants (match reference)
constexpr int B = 16;
constexpr int N = 100000;
constexpr int E = 10;
constexpr int D = 3;

typedef float        f32x4 __attribute__((ext_vector_type(4)));
typedef unsigned int u32x4 __attribute__((ext_vector_type(4)));

__device__ __forceinline__ unsigned int bf16_rne(float f) {
    unsigned int u = __float_as_uint(f);
    u += 0x7fffu + ((u >> 16) & 1u);   // round-to-nearest-even
    return u >> 16;
}
__device__ __forceinline__ float bf16_lo(unsigned long long w) {
    return __uint_as_float((unsigned int)w << 16);
}
__device__ __forceinline__ float bf16_hi(unsigned long long w) {
    return __uint_as_float((unsigned int)w & 0xffff0000u);
}
__device__ __forceinline__ float bf16_w2(unsigned long long w) {
    return __uint_as_float((unsigned int)(w >> 32) << 16);
}

// ---------------------------------------------------------------------------
// diff kernel: diff = coord2 - coord1 packed as bf16 {x,y,z,pad} 8B/node.
// Also zeroes the output accumulator (replaces the memset dispatch).
// ---------------------------------------------------------------------------
__global__ __launch_bounds__(256) void diff_bf16_kernel(const float* __restrict__ c1,
                                                        const float* __restrict__ c2,
                                                        unsigned int* __restrict__ outp,
                                                        float* __restrict__ out,
                                                        int nquad) {  // B*N/4
    if (blockIdx.x == 0 && threadIdx.x == 0) *out = 0.0f;
    int per = gridDim.x >> 3;
    int w = (blockIdx.x & 7) * per + (blockIdx.x >> 3);
    int i = w * blockDim.x + threadIdx.x;
    if (i >= nquad) return;
    const f32x4* a4 = reinterpret_cast<const f32x4*>(c1) + (size_t)i * 3;
    const f32x4* b4 = reinterpret_cast<const f32x4*>(c2) + (size_t)i * 3;
    f32x4 a0 = __builtin_nontemporal_load(a4 + 0);
    f32x4 a1 = __builtin_nontemporal_load(a4 + 1);
    f32x4 a2 = __builtin_nontemporal_load(a4 + 2);
    f32x4 b0 = __builtin_nontemporal_load(b4 + 0);
    f32x4 b1 = __builtin_nontemporal_load(b4 + 1);
    f32x4 b2 = __builtin_nontemporal_load(b4 + 2);
    float d[12];
    d[0] = b0.x - a0.x; d[1] = b0.y - a0.y; d[2]  = b0.z - a0.z; d[3]  = b0.w - a0.w;
    d[4] = b1.x - a1.x; d[5] = b1.y - a1.y; d[6]  = b1.z - a1.z; d[7]  = b1.w - a1.w;
    d[8] = b2.x - a2.x; d[9] = b2.y - a2.y; d[10] = b2.z - a2.z; d[11] = b2.w - a2.w;

    u32x4 o0, o1;
    o0.x = bf16_rne(d[0]) | (bf16_rne(d[1]) << 16);   // node 4i
    o0.y = bf16_rne(d[2]);
    o0.z = bf16_rne(d[3]) | (bf16_rne(d[4]) << 16);   // node 4i+1
    o0.w = bf16_rne(d[5]);
    o1.x = bf16_rne(d[6]) | (bf16_rne(d[7]) << 16);   // node 4i+2
    o1.y = bf16_rne(d[8]);
    o1.z = bf16_rne(d[9]) | (bf16_rne(d[10]) << 16);  // node 4i+3
    o1.w = bf16_rne(d[11]);

    u32x4* o = reinterpret_cast<u32x4*>(outp) + (size_t)i * 2;
    o[0] = o0;
    o[1] = o1;
}

// ---------------------------------------------------------------------------
// loss kernel: per-node laplacian-of-diff squared -> block reduce -> atomicAdd
// Gathers: one asm block of 10 back-to-back global_load_dwordx2 with sc0
// (no L1 allocation -> no per-CU L1-MSHR occupancy; served from L2, which
// keeps the slab resident since each line is reused ~80x per XCD).
// Ends with s_waitcnt vmcnt(0) so compiler vmcnt accounting stays exact.
// ---------------------------------------------------------------------------
__global__ __launch_bounds__(256, 8) void loss_kernel(const unsigned int* __restrict__ diff,
                                                      const int* __restrict__ A,
                                                      float* __restrict__ out) {
    int per = gridDim.x >> 3;
    int w = (blockIdx.x & 7) * per + (blockIdx.x >> 3);
    int node = w * blockDim.x + threadIdx.x;

    float sq = 0.0f;
    if (node < B * N) {
        int b = node / N;  // magic-mul
        // A row: 10 ints, 40B, 8B-aligned; nt (stream-once)
        const long long* ap = reinterpret_cast<const long long*>(A + (size_t)node * E);
        long long q0 = __builtin_nontemporal_load(ap + 0);
        long long q1 = __builtin_nontemporal_load(ap + 1);
        long long q2 = __builtin_nontemporal_load(ap + 2);
        long long q3 = __builtin_nontemporal_load(ap + 3);
        long long q4 = __builtin_nontemporal_load(ap + 4);
        int idx[E] = {(int)q0, (int)(q0 >> 32), (int)q1, (int)(q1 >> 32),
                      (int)q2, (int)(q2 >> 32), (int)q3, (int)(q3 >> 32),
                      (int)q4, (int)(q4 >> 32)};

        const unsigned long long* db =
            reinterpret_cast<const unsigned long long*>(diff) + (size_t)b * N;

        float m[E];
        const unsigned long long* p[E];
        #pragma unroll
        for (int e = 0; e < E; ++e) {
            int ix = idx[e];
            m[e] = (ix >= 0) ? 1.0f : 0.0f;
            p[e] = db + (ix >= 0 ? ix : 0);
        }

        unsigned long long g0, g1, g2, g3, g4, g5, g6, g7, g8, g9;
        asm volatile(
            "global_load_dwordx2 %0, %10, off sc0\n\t"
            "global_load_dwordx2 %1, %11, off sc0\n\t"
            "global_load_dwordx2 %2, %12, off sc0\n\t"
            "global_load_dwordx2 %3, %13, off sc0\n\t"
            "global_load_dwordx2 %4, %14, off sc0\n\t"
            "global_load_dwordx2 %5, %15, off sc0\n\t"
            "global_load_dwordx2 %6, %16, off sc0\n\t"
            "global_load_dwordx2 %7, %17, off sc0\n\t"
            "global_load_dwordx2 %8, %18, off sc0\n\t"
            "global_load_dwordx2 %9, %19, off sc0\n\t"
            "s_waitcnt vmcnt(0)"
            : "=&v"(g0), "=&v"(g1), "=&v"(g2), "=&v"(g3), "=&v"(g4),
              "=&v"(g5), "=&v"(g6), "=&v"(g7), "=&v"(g8), "=&v"(g9)
            : "v"(p[0]), "v"(p[1]), "v"(p[2]), "v"(p[3]), "v"(p[4]),
              "v"(p[5]), "v"(p[6]), "v"(p[7]), "v"(p[8]), "v"(p[9])
            : "memory");

        unsigned long long gv[E] = {g0, g1, g2, g3, g4, g5, g6, g7, g8, g9};
        unsigned long long ov = db[node - b * N];   // coalesced own read

        float sx = 0.f, sy = 0.f, sz = 0.f, fcnt = 0.f;
        #pragma unroll
        for (int e = 0; e < E; ++e) {
            sx = fmaf(bf16_lo(gv[e]), m[e], sx);
            sy = fmaf(bf16_hi(gv[e]), m[e], sy);
            sz = fmaf(bf16_w2(gv[e]), m[e], sz);
            fcnt += m[e];
        }
        float inv = 1.0f / fcnt;           // fcnt >= 1 (slot 0 valid)
        float lx = bf16_lo(ov) - sx * inv;
        float ly = bf16_hi(ov) - sy * inv;
        float lz = bf16_w2(ov) - sz * inv;
        sq = lx * lx + ly * ly + lz * lz;
    }

    #pragma unroll
    for (int off = 32; off > 0; off >>= 1)
        sq += __shfl_down(sq, off, 64);

    __shared__ float wsum[4];
    int lane = threadIdx.x & 63;
    int wid = threadIdx.x >> 6;
    if (lane == 0) wsum[wid] = sq;
    __syncthreads();
    if (threadIdx.x == 0) {
        float t = (wsum[0] + wsum[1]) + (wsum[2] + wsum[3]);
        // loss = sum/(B*N*D) * N = sum/(B*D)
        atomicAdd(out, t * (1.0f / (float)(B * D)));
    }
}

extern "C" void kernel_launch(void* const* d_in, const int* in_sizes, int n_in,
                              void* d_out, int out_size, void* d_ws, size_t ws_size,
                              hipStream_t stream) {
    const float* coord1 = (const float*)d_in[0];
    const float* coord2 = (const float*)d_in[1];
    const int* A_list = (const int*)d_in[2];
    float* out = (float*)d_out;
    unsigned int* diff = (unsigned int*)d_ws;   // B*N*8 bytes = 12.8 MB

    int nodes = B * N;       // 1.6M
    int nquad = nodes / 4;   // 400000
    int dblk = (nquad + 255) / 256;  // 1563
    dblk = (dblk + 7) & ~7;          // 1568, multiple of 8 for swizzle
    diff_bf16_kernel<<<dblk, 256, 0, stream>>>(coord1, coord2, diff, out, nquad);

    int nblk = (nodes + 255) / 256;  // 6250
    nblk = (nblk + 7) & ~7;          // 6256
    loss_kernel<<<nblk, 256, 0, stream>>>(diff, A_list, out);
}